// Round 6
// baseline (215.829 us; speedup 1.0000x reference)
//
#include <hip/hip_runtime.h>

// Scaled dot-product attention, B=2 H=12 S=2048 D=64, fp32 in/out.
// Outputs: out [B,H,S,D] then we [B,H,S,S] concatenated in d_out.
// R5: t-split x2 for occupancy (12 -> 24 waves/CU).
//   k1 (grid 1536): partial softmax denominators -> atomicAdd to d_ws.
//   k2 (grid 1536): recompute logits, write we half (coalesced f32x4),
//                   PV partial -> atomicAdd into out.
// Per-iter structure identical to validated R4 (swapped QK^T, K/V^T
// XOR-swizzled LDS, double-buffer + issue-early prefetch).

typedef short          s16x8 __attribute__((ext_vector_type(8)));
typedef unsigned short u16x8 __attribute__((ext_vector_type(8)));
typedef unsigned short u16x4 __attribute__((ext_vector_type(4)));
typedef float          f32x4 __attribute__((ext_vector_type(4)));

#define kS   2048
#define kD   64
#define kBH  24
#define kTH  1024                    // t-half length
#define OUT_ELEMS (kBH * kS * kD)    // 3145728

static __device__ __forceinline__ unsigned short f2bf(float f) {
    union { float f; unsigned u; } x; x.f = f;
    return (unsigned short)((x.u + 0x7fffu + ((x.u >> 16) & 1u)) >> 16); // RNE
}

static __device__ __forceinline__ u16x8 cvt8(const float4 f0, const float4 f1) {
    u16x8 r;
    r[0] = f2bf(f0.x); r[1] = f2bf(f0.y); r[2] = f2bf(f0.z); r[3] = f2bf(f0.w);
    r[4] = f2bf(f1.x); r[5] = f2bf(f1.y); r[6] = f2bf(f1.z); r[7] = f2bf(f1.w);
    return r;
}

// decode swizzled block id -> (bh, qb, th); 1536 blocks, 192/XCD = 3 heads
static __device__ __forceinline__ void decode(int bid, int& bh, int& qb, int& th) {
    const int wg = (bid & 7) * 192 + (bid >> 3);
    bh = wg >> 6;
    qb = (wg & 63) >> 1;
    th = wg & 1;
}

// ======================= kernel 1: denominators =======================
__global__ __launch_bounds__(256)
void attn_p1(const float* __restrict__ Qg, const float* __restrict__ Kg,
             const float* __restrict__ Mg, float* __restrict__ denom)
{
    __shared__ __align__(16) unsigned short k_sh[2][32 * 64];

    const int tid  = threadIdx.x;
    const int wv   = tid >> 6;
    const int lane = tid & 63;
    const int g    = lane >> 4;
    const int c    = lane & 15;

    int bh, qb, th; decode((int)blockIdx.x, bh, qb, th);
    const int q0 = qb * 64 + wv * 16;
    const int tb = th * kTH;

    s16x8 aQ[2];
    {
        const float* qp = Qg + ((size_t)(bh * kS + q0 + c)) * kD + g * 8;
        #pragma unroll
        for (int h = 0; h < 2; ++h) {
            float4 f0 = *(const float4*)(qp + h * 32);
            float4 f1 = *(const float4*)(qp + h * 32 + 4);
            union { u16x8 u; s16x8 s; } t; t.u = cvt8(f0, f1);
            aQ[h] = t.s;
        }
    }

    const int sr = tid >> 3;
    const int sc = (tid & 7) * 8;
    const float* kstage = Kg + ((size_t)(bh * kS + tb + sr)) * kD + sc;
    const unsigned kaddr_w = (unsigned)((sr * 128 + sc * 2) ^ ((sr & 7) << 4));
    const float* mrow = Mg + (size_t)(q0 + c) * kS + tb;

    {
        *(u16x8*)((char*)k_sh[0] + kaddr_w) = cvt8(*(const float4*)kstage, *(const float4*)(kstage + 4));
    }
    __syncthreads();

    float sm = 0.f;
    int cur = 0;
    for (int t0 = 0; t0 < kTH; t0 += 32) {
        const bool nxt = (t0 + 32) < kTH;
        float4 kf0, kf1;
        if (nxt) {
            const float* src = kstage + (size_t)(t0 + 32) * kD;
            kf0 = *(const float4*)src; kf1 = *(const float4*)(src + 4);
        }
        #pragma unroll
        for (int tt = 0; tt < 2; ++tt) {
            const int row = tt * 16 + c;
            f32x4 acc = {0.f, 0.f, 0.f, 0.f};
            #pragma unroll
            for (int h = 0; h < 2; ++h) {
                const unsigned a = (unsigned)((row * 128 + h * 64 + g * 16) ^ ((row & 7) << 4));
                s16x8 bK = *(const s16x8*)((const char*)k_sh[cur] + a);
                acc = __builtin_amdgcn_mfma_f32_16x16x32_bf16(bK, aQ[h], acc, 0, 0, 0);
            }
            const float4 mk = *(const float4*)(mrow + t0 + tt * 16 + g * 4);
            sm += __expf(acc[0] * 0.125f + mk.x);
            sm += __expf(acc[1] * 0.125f + mk.y);
            sm += __expf(acc[2] * 0.125f + mk.z);
            sm += __expf(acc[3] * 0.125f + mk.w);
        }
        if (nxt) {
            *(u16x8*)((char*)k_sh[cur ^ 1] + kaddr_w) = cvt8(kf0, kf1);
            __syncthreads();
            cur ^= 1;
        }
    }
    sm += __shfl_xor(sm, 16);
    sm += __shfl_xor(sm, 32);
    if (g == 0)
        atomicAdd(denom + bh * kS + q0 + c, sm);
}

// ================= kernel 2: we write + partial PV =================
__global__ __launch_bounds__(256)
void attn_p2(const float* __restrict__ Qg, const float* __restrict__ Kg,
             const float* __restrict__ Vg, const float* __restrict__ Mg,
             const float* __restrict__ denom,
             float* __restrict__ Og, float* __restrict__ Wg)
{
    __shared__ __align__(16) unsigned short k_sh[2][32 * 64];
    __shared__ __align__(16) unsigned short vt_sh[2][64 * 32];
    __shared__ __align__(16) unsigned short p_sh[4][16 * 40];

    const int tid  = threadIdx.x;
    const int wv   = tid >> 6;
    const int lane = tid & 63;
    const int g    = lane >> 4;
    const int c    = lane & 15;

    int bh, qb, th; decode((int)blockIdx.x, bh, qb, th);
    const int q0 = qb * 64 + wv * 16;
    const int tb = th * kTH;

    s16x8 aQ[2];
    {
        const float* qp = Qg + ((size_t)(bh * kS + q0 + c)) * kD + g * 8;
        #pragma unroll
        for (int h = 0; h < 2; ++h) {
            float4 f0 = *(const float4*)(qp + h * 32);
            float4 f1 = *(const float4*)(qp + h * 32 + 4);
            union { u16x8 u; s16x8 s; } t; t.u = cvt8(f0, f1);
            aQ[h] = t.s;
        }
    }

    const int sr = tid >> 3;
    const int sc = (tid & 7) * 8;
    const float* kstage = Kg + ((size_t)(bh * kS + tb + sr)) * kD + sc;
    const float* vstage = Vg + ((size_t)(bh * kS + tb + sr)) * kD + sc;
    const unsigned kaddr_w = (unsigned)((sr * 128 + sc * 2) ^ ((sr & 7) << 4));
    const float* mrow = Mg + (size_t)(q0 + c) * kS + tb;

    const float sminv = 1.0f / denom[bh * kS + q0 + c];

    f32x4 accO[4];
    #pragma unroll
    for (int dt = 0; dt < 4; ++dt) accO[dt] = f32x4{0.f, 0.f, 0.f, 0.f};

    float* wrow = Wg + ((size_t)(bh * kS + q0 + c)) * kS + tb;

    {
        *(u16x8*)((char*)k_sh[0] + kaddr_w) = cvt8(*(const float4*)kstage, *(const float4*)(kstage + 4));
        u16x8 vb = cvt8(*(const float4*)vstage, *(const float4*)(vstage + 4));
        #pragma unroll
        for (int i = 0; i < 8; ++i) {
            const int d = sc + i;
            const unsigned b = (unsigned)((d * 64 + sr * 2) ^ (((d >> 3) & 7) << 4));
            *(unsigned short*)((char*)vt_sh[0] + b) = vb[i];
        }
    }
    __syncthreads();

    int cur = 0;
    for (int t0 = 0; t0 < kTH; t0 += 32) {
        const bool nxt = (t0 + 32) < kTH;
        float4 kf0, kf1, vf0, vf1;
        if (nxt) {
            const float* srck = kstage + (size_t)(t0 + 32) * kD;
            kf0 = *(const float4*)srck; kf1 = *(const float4*)(srck + 4);
            const float* srcv = vstage + (size_t)(t0 + 32) * kD;
            vf0 = *(const float4*)srcv; vf1 = *(const float4*)(srcv + 4);
        }

        #pragma unroll
        for (int tt = 0; tt < 2; ++tt) {
            const int row = tt * 16 + c;
            f32x4 acc = {0.f, 0.f, 0.f, 0.f};
            #pragma unroll
            for (int h = 0; h < 2; ++h) {
                const unsigned a = (unsigned)((row * 128 + h * 64 + g * 16) ^ ((row & 7) << 4));
                s16x8 bK = *(const s16x8*)((const char*)k_sh[cur] + a);
                acc = __builtin_amdgcn_mfma_f32_16x16x32_bf16(bK, aQ[h], acc, 0, 0, 0);
            }
            const float4 mk = *(const float4*)(mrow + t0 + tt * 16 + g * 4);
            f32x4 p;
            p[0] = __expf(acc[0] * 0.125f + mk.x) * sminv;
            p[1] = __expf(acc[1] * 0.125f + mk.y) * sminv;
            p[2] = __expf(acc[2] * 0.125f + mk.z) * sminv;
            p[3] = __expf(acc[3] * 0.125f + mk.w) * sminv;
            __builtin_nontemporal_store(p, (f32x4*)(wrow + t0 + tt * 16 + g * 4));
            u16x4 pb;
            pb[0] = f2bf(p[0]); pb[1] = f2bf(p[1]); pb[2] = f2bf(p[2]); pb[3] = f2bf(p[3]);
            *(u16x4*)&p_sh[wv][c * 40 + tt * 16 + g * 4] = pb;
        }

        s16x8 pa = *(const s16x8*)((const char*)&p_sh[wv][0] + c * 80 + g * 16);
        #pragma unroll
        for (int dt = 0; dt < 4; ++dt) {
            const int d = dt * 16 + c;
            const unsigned b = (unsigned)((d * 64 + g * 16) ^ (((d >> 3) & 7) << 4));
            s16x8 bV = *(const s16x8*)((const char*)vt_sh[cur] + b);
            accO[dt] = __builtin_amdgcn_mfma_f32_16x16x32_bf16(pa, bV, accO[dt], 0, 0, 0);
        }

        if (nxt) {
            *(u16x8*)((char*)k_sh[cur ^ 1] + kaddr_w) = cvt8(kf0, kf1);
            u16x8 vb = cvt8(vf0, vf1);
            #pragma unroll
            for (int i = 0; i < 8; ++i) {
                const int d = sc + i;
                const unsigned b = (unsigned)((d * 64 + sr * 2) ^ (((d >> 3) & 7) << 4));
                *(unsigned short*)((char*)vt_sh[cur ^ 1] + b) = vb[i];
            }
            __syncthreads();
            cur ^= 1;
        }
    }

    // partial-PV combine across the two t-halves
    float* orow = Og + ((size_t)(bh * kS + q0 + g * 4)) * kD + c;
    #pragma unroll
    for (int dt = 0; dt < 4; ++dt) {
        #pragma unroll
        for (int j = 0; j < 4; ++j)
            atomicAdd(orow + (size_t)j * kD + dt * 16, accO[dt][j]);
    }
}

extern "C" void kernel_launch(void* const* d_in, const int* in_sizes, int n_in,
                              void* d_out, int out_size, void* d_ws, size_t ws_size,
                              hipStream_t stream) {
    const float* q = (const float*)d_in[0];
    const float* k = (const float*)d_in[1];
    const float* v = (const float*)d_in[2];
    const float* m = (const float*)d_in[3];
    float* out   = (float*)d_out;
    float* we    = out + OUT_ELEMS;
    float* denom = (float*)d_ws;                       // 24*2048 f32 = 196 KB

    hipMemsetAsync(denom, 0, (size_t)kBH * kS * sizeof(float), stream);
    hipMemsetAsync(out,   0, (size_t)OUT_ELEMS * sizeof(float), stream);
    attn_p1<<<dim3(kBH * 64), dim3(256), 0, stream>>>(q, k, m, denom);
    attn_p2<<<dim3(kBH * 64), dim3(256), 0, stream>>>(q, k, v, m, denom, out, we);
}

// Round 7
// 198.320 us; speedup vs baseline: 1.0883x; 1.0883x over previous
//
#include <hip/hip_runtime.h>

// Scaled dot-product attention, B=2 H=12 S=2048 D=64, fp32 in/out.
// Outputs: out [B,H,S,D] then we [B,H,S,S] concatenated in d_out.
// R6 = validated R2 inner structure + (a) vt_sh XOR swizzle (kills the
// 16-way scatter conflict), (b) 8-wave blocks: 4 q-subtiles x 2 t-halves
// per block -> 24 waves/CU (was 12). Denom/PV halves combined in LDS.
// One kernel, no scratch, no memsets.

typedef short          s16x8 __attribute__((ext_vector_type(8)));
typedef unsigned short u16x8 __attribute__((ext_vector_type(8)));
typedef float          f32x4 __attribute__((ext_vector_type(4)));

#define kS   2048
#define kD   64
#define kBH  24
#define kTH  1024                    // per-group t-half
#define OUT_ELEMS (kBH * kS * kD)    // 3145728

// LDS pool layout (bytes)
#define K_OFF   0        // 2 groups x 32x64 u16 = 2 x 8192
#define VT_OFF  16384    // 2 groups x 64x32 u16 = 2 x 8192
#define P_OFF   32768    // 8 waves x 16x40 u16  = 8 x 1280
#define SM_OFF  43008    // 128 f32 denominator table
#define POOL_SZ 43520    // 42.5 KB -> 3 blocks/CU

static __device__ __forceinline__ unsigned short f2bf(float f) {
    union { float f; unsigned u; } x; x.f = f;
    return (unsigned short)((x.u + 0x7fffu + ((x.u >> 16) & 1u)) >> 16); // RNE
}

static __device__ __forceinline__ u16x8 cvt8(const float4 f0, const float4 f1) {
    u16x8 r;
    r[0] = f2bf(f0.x); r[1] = f2bf(f0.y); r[2] = f2bf(f0.z); r[3] = f2bf(f0.w);
    r[4] = f2bf(f1.x); r[5] = f2bf(f1.y); r[6] = f2bf(f1.z); r[7] = f2bf(f1.w);
    return r;
}

__global__ __launch_bounds__(512)
void attn_fused(const float* __restrict__ Qg, const float* __restrict__ Kg,
                const float* __restrict__ Vg, const float* __restrict__ Mg,
                float* __restrict__ Og, float* __restrict__ Wg)
{
    __shared__ __align__(16) unsigned char pool[POOL_SZ];

    const int tid  = threadIdx.x;
    const int wv   = tid >> 6;       // 0..7
    const int qsub = wv & 3;         // q sub-tile
    const int th   = wv >> 2;        // t-half
    const int lane = tid & 63;
    const int g    = lane >> 4;
    const int c    = lane & 15;

    // XCD-bijective swizzle: 768 blocks, 96/XCD
    const int wg = ((int)blockIdx.x & 7) * 96 + ((int)blockIdx.x >> 3);
    const int bh = wg >> 5;
    const int qb = wg & 31;
    const int q0 = qb * 64 + qsub * 16;
    const int tb = th * kTH;

    unsigned short* k_sh  = (unsigned short*)(pool + K_OFF)  + th * (32 * 64);
    unsigned short* vt_sh = (unsigned short*)(pool + VT_OFF) + th * (64 * 32);
    unsigned short* p_shw = (unsigned short*)(pool + P_OFF)  + wv * (16 * 40);
    float*          sm_sh = (float*)(pool + SM_OFF);

    // ---- Q A-frag: row = q0+c, k = h*32 + g*8 + j (validated R2) ----
    s16x8 aQ[2];
    {
        const float* qp = Qg + ((size_t)(bh * kS + q0 + c)) * kD + g * 8;
        #pragma unroll
        for (int h = 0; h < 2; ++h) {
            float4 f0 = *(const float4*)(qp + h * 32);
            float4 f1 = *(const float4*)(qp + h * 32 + 4);
            union { u16x8 u; s16x8 s; } t; t.u = cvt8(f0, f1);
            aQ[h] = t.s;
        }
    }

    // staging: group-local thread -> (row sr, cols sc..sc+7) of 32x64 tile
    const int tg = tid & 255;
    const int sr = tg >> 3;
    const int sc = (tg & 7) * 8;
    const float* kstage = Kg + ((size_t)(bh * kS + tb + sr)) * kD + sc;
    const float* vstage = Vg + ((size_t)(bh * kS + tb + sr)) * kD + sc;
    const unsigned kaddr_w = (unsigned)((sr * 128 + sc * 2) ^ ((sr & 7) << 4));
    const float* mrow = Mg + (size_t)(q0 + g * 4) * kS + tb;

    // ================= pass 1: partial softmax denominators =================
    float sm[4] = {0.f, 0.f, 0.f, 0.f};
    for (int t0 = 0; t0 < kTH; t0 += 32) {
        __syncthreads();
        {
            const float* src = kstage + (size_t)t0 * kD;
            *(u16x8*)((char*)k_sh + kaddr_w) = cvt8(*(const float4*)src, *(const float4*)(src + 4));
        }
        __syncthreads();
        #pragma unroll
        for (int tt = 0; tt < 2; ++tt) {
            const int row = tt * 16 + c;
            f32x4 acc = {0.f, 0.f, 0.f, 0.f};
            #pragma unroll
            for (int h = 0; h < 2; ++h) {
                const unsigned a = (unsigned)((row * 128 + h * 64 + g * 16) ^ ((row & 7) << 4));
                s16x8 bK = *(const s16x8*)((const char*)k_sh + a);
                acc = __builtin_amdgcn_mfma_f32_16x16x32_bf16(aQ[h], bK, acc, 0, 0, 0);
            }
            const int t = t0 + tt * 16 + c;
            #pragma unroll
            for (int j = 0; j < 4; ++j)
                sm[j] += __expf(acc[j] * 0.125f + mrow[(size_t)j * kS + t]);
        }
    }
    #pragma unroll
    for (int j = 0; j < 4; ++j) {   // reduce over the 16 column-lanes
        float s = sm[j];
        s += __shfl_xor(s, 1);
        s += __shfl_xor(s, 2);
        s += __shfl_xor(s, 4);
        s += __shfl_xor(s, 8);
        sm[j] = s;
    }
    // cross-half combine via LDS table
    if (c == 0) {
        #pragma unroll
        for (int j = 0; j < 4; ++j)
            sm_sh[wv * 16 + g * 4 + j] = sm[j];
    }
    __syncthreads();
    float sminv[4];
    #pragma unroll
    for (int j = 0; j < 4; ++j)
        sminv[j] = 1.0f / (sm_sh[qsub * 16 + g * 4 + j] + sm_sh[64 + qsub * 16 + g * 4 + j]);

    // ================= pass 2: write we half, accumulate PV =================
    f32x4 accO[4];
    #pragma unroll
    for (int dt = 0; dt < 4; ++dt) accO[dt] = f32x4{0.f, 0.f, 0.f, 0.f};

    float* wrow = Wg + ((size_t)(bh * kS + q0 + g * 4)) * kS + tb;

    for (int t0 = 0; t0 < kTH; t0 += 32) {
        __syncthreads();
        {
            const float* srck = kstage + (size_t)t0 * kD;
            *(u16x8*)((char*)k_sh + kaddr_w) = cvt8(*(const float4*)srck, *(const float4*)(srck + 4));
            const float* srcv = vstage + (size_t)t0 * kD;
            u16x8 vb = cvt8(*(const float4*)srcv, *(const float4*)(srcv + 4));
            #pragma unroll
            for (int i = 0; i < 8; ++i) {   // V^T scatter, swizzled (2-way = free)
                const int d = sc + i;
                const unsigned b = (unsigned)((d * 64 + sr * 2) ^ (((d >> 3) & 7) << 4));
                *(unsigned short*)((char*)vt_sh + b) = vb[i];
            }
        }
        __syncthreads();

        #pragma unroll
        for (int tt = 0; tt < 2; ++tt) {
            const int row = tt * 16 + c;
            f32x4 acc = {0.f, 0.f, 0.f, 0.f};
            #pragma unroll
            for (int h = 0; h < 2; ++h) {
                const unsigned a = (unsigned)((row * 128 + h * 64 + g * 16) ^ ((row & 7) << 4));
                s16x8 bK = *(const s16x8*)((const char*)k_sh + a);
                acc = __builtin_amdgcn_mfma_f32_16x16x32_bf16(aQ[h], bK, acc, 0, 0, 0);
            }
            const int t = t0 + tt * 16 + c;
            #pragma unroll
            for (int j = 0; j < 4; ++j) {
                const float p = __expf(acc[j] * 0.125f + mrow[(size_t)j * kS + t]) * sminv[j];
                __builtin_nontemporal_store(p, wrow + (size_t)j * kS + t);
                p_shw[(g * 4 + j) * 40 + tt * 16 + c] = f2bf(p);
            }
        }

        // A-frag of P: row=c, k=g*8+j (validated R2 read)
        s16x8 pa = *(const s16x8*)((const char*)p_shw + c * 80 + g * 16);
        #pragma unroll
        for (int dt = 0; dt < 4; ++dt) {
            const int d = dt * 16 + c;
            const unsigned b = (unsigned)((d * 64 + g * 16) ^ (((d >> 3) & 7) << 4));
            s16x8 bV = *(const s16x8*)((const char*)vt_sh + b);
            accO[dt] = __builtin_amdgcn_mfma_f32_16x16x32_bf16(pa, bV, accO[dt], 0, 0, 0);
        }
    }

    // ===== epilogue: combine PV halves in LDS (reuse dead K/V region) =====
    __syncthreads();                      // all tile reads complete
    float* oacc = (float*)pool;           // [0, 20480) — stride 20 fl/lane
    if (th == 1) {
        #pragma unroll
        for (int dt = 0; dt < 4; ++dt)
            #pragma unroll
            for (int j = 0; j < 4; ++j)
                oacc[(qsub * 64 + lane) * 20 + dt * 4 + j] = accO[dt][j];
    }
    __syncthreads();
    if (th == 0) {
        float* orow = Og + ((size_t)(bh * kS + q0 + g * 4)) * kD + c;
        #pragma unroll
        for (int dt = 0; dt < 4; ++dt)
            #pragma unroll
            for (int j = 0; j < 4; ++j) {
                const float v = accO[dt][j] + oacc[(qsub * 64 + lane) * 20 + dt * 4 + j];
                __builtin_nontemporal_store(v, orow + (size_t)j * kD + dt * 16);
            }
    }
}

extern "C" void kernel_launch(void* const* d_in, const int* in_sizes, int n_in,
                              void* d_out, int out_size, void* d_ws, size_t ws_size,
                              hipStream_t stream) {
    const float* q = (const float*)d_in[0];
    const float* k = (const float*)d_in[1];
    const float* v = (const float*)d_in[2];
    const float* m = (const float*)d_in[3];
    float* out = (float*)d_out;
    float* we  = out + OUT_ELEMS;
    attn_fused<<<dim3(kBH * 32), dim3(512), 0, stream>>>(q, k, v, m, out, we);
}